// Round 6
// baseline (709.968 us; speedup 1.0000x reference)
//
#include <hip/hip_runtime.h>
#include <hip/hip_bf16.h>
#include <stdint.h>

typedef unsigned short u16;
typedef __attribute__((ext_vector_type(8))) __bf16 bf16x8;
typedef __attribute__((ext_vector_type(4))) float f32x4;
typedef __attribute__((ext_vector_type(4))) unsigned int u32x4;

#define S_LEN 2048
#define NHEAD 16
#define HDIM 64
#define DMODEL 1024
#define NBATCH 4
#define MTOK (NBATCH * S_LEN)   // 8192

// ---------- helpers ----------
__device__ __forceinline__ u16 f2bf(float f) {
    uint32_t u = __float_as_uint(f);
    u += 0x7fffu + ((u >> 16) & 1u);   // RNE
    return (u16)(u >> 16);
}

// async global->LDS, 16B per lane; lds dest must be wave-uniform base (+lane*16)
__device__ __forceinline__ void gld_lds16(const u16* g, u16* l) {
    __builtin_amdgcn_global_load_lds(
        (const __attribute__((address_space(1))) void*)g,
        (__attribute__((address_space(3))) void*)l, 16, 0, 0);
}

// ---------- fused fp32 -> bf16 cast: all 7 tensors in one launch ----------
__global__ __launch_bounds__(256) void cast_all(
        const float* __restrict__ q, const float* __restrict__ k, const float* __restrict__ v,
        const float* __restrict__ wq, const float* __restrict__ wk,
        const float* __restrict__ wv, const float* __restrict__ wo,
        u16* __restrict__ xq, u16* __restrict__ xk, u16* __restrict__ xv,
        u16* __restrict__ wqb, u16* __restrict__ wkb, u16* __restrict__ wvb,
        u16* __restrict__ wob) {
    size_t idx4 = (size_t)blockIdx.x * 256 + threadIdx.x;   // float4 index
    const float* src;
    u16* dst;
    size_t off;
    if (idx4 < (size_t)3 << 21) {
        int t = (int)(idx4 >> 21);
        off = (idx4 & ((1u << 21) - 1)) * 4;
        src = (t == 0) ? q : (t == 1) ? k : v;
        dst = (t == 0) ? xq : (t == 1) ? xk : xv;
    } else {
        size_t w = idx4 - ((size_t)3 << 21);
        int t = (int)(w >> 18);
        off = (w & ((1u << 18) - 1)) * 4;
        src = (t == 0) ? wq : (t == 1) ? wk : (t == 2) ? wv : wo;
        dst = (t == 0) ? wqb : (t == 1) ? wkb : (t == 2) ? wvb : wob;
    }
    float4 val = *(const float4*)(src + off);
    ushort4 o;
    o.x = f2bf(val.x); o.y = f2bf(val.y); o.z = f2bf(val.z); o.w = f2bf(val.w);
    *(ushort4*)(dst + off) = o;
}

// ---------- GEMM: out[m,n] = sum_k A[m,k]*W[n,k] + bias[n] ----------
// XOR-swizzled LDS (R5): conflict-free b128 fragment reads.
#define TM 128
#define TN 128

__device__ __forceinline__ void gemm_body(const u16* __restrict__ A,
                                          const u16* __restrict__ W,
                                          const float* __restrict__ bias,
                                          void* __restrict__ outp, int mode,
                                          int m0, int n0) {
    __shared__ __align__(16) u16 As[TM * 32];
    __shared__ __align__(16) u16 Bs[TN * 32];
    const int tid  = threadIdx.x;
    const int lane = tid & 63;
    const int wv   = tid >> 6;
    const int l16  = lane & 15;
    const int quad = lane >> 4;
    const int wm   = (wv >> 1) * 64;
    const int wn   = (wv & 1) * 64;

    f32x4 acc[4][4];
#pragma unroll
    for (int i = 0; i < 4; i++)
#pragma unroll
        for (int j = 0; j < 4; j++) acc[i][j] = {};

    const int arow = wv * 16 + (lane >> 2);
    const int acol = ((lane & 3) ^ ((lane >> 3) & 3)) * 8;   // swizzled source col
    const u16* gA = A + (size_t)(m0 + arow) * DMODEL + acol;
    const u16* gB = W + (size_t)(n0 + arow) * DMODEL + acol;
    u16* lA = As + wv * 16 * 32;   // wave-uniform
    u16* lB = Bs + wv * 16 * 32;

    const int swz = (l16 >> 1) & 3;   // fragment-read swizzle

    for (int kb = 0; kb < DMODEL; kb += 32) {
        gld_lds16(gA + kb, lA);
        gld_lds16(gA + kb + (size_t)64 * DMODEL, lA + 64 * 32);
        gld_lds16(gB + kb, lB);
        gld_lds16(gB + kb + (size_t)64 * DMODEL, lB + 64 * 32);
        __builtin_amdgcn_s_waitcnt(0x0F70);   // vmcnt(0)
        __syncthreads();

        bf16x8 af[4], bfv[4];
#pragma unroll
        for (int i = 0; i < 4; i++)
            af[i] = *(const bf16x8*)(&As[(wm + i * 16 + l16) * 32 + (quad ^ swz) * 8]);
#pragma unroll
        for (int j = 0; j < 4; j++)
            bfv[j] = *(const bf16x8*)(&Bs[(wn + j * 16 + l16) * 32 + (quad ^ swz) * 8]);
#pragma unroll
        for (int i = 0; i < 4; i++)
#pragma unroll
            for (int j = 0; j < 4; j++)
                acc[i][j] = __builtin_amdgcn_mfma_f32_16x16x32_bf16(af[i], bfv[j], acc[i][j], 0, 0, 0);
        __syncthreads();
    }

#pragma unroll
    for (int j = 0; j < 4; j++) {
        int n = n0 + wn + j * 16 + l16;
        float bv = bias[n];
#pragma unroll
        for (int i = 0; i < 4; i++) {
            int mbase = m0 + wm + i * 16 + quad * 4;
#pragma unroll
            for (int r = 0; r < 4; r++) {
                int m = mbase + r;
                float v = acc[i][j][r] + bv;
                if (mode == 2) {
                    ((float*)outp)[(size_t)m * DMODEL + n] = v;
                } else {
                    int b = m >> 11, s = m & (S_LEN - 1);
                    int h = n >> 6, d = n & 63;
                    u16* o = (u16*)outp;
                    size_t idx = (mode == 0)
                        ? ((((size_t)(b * NHEAD + h)) * S_LEN + s) * HDIM + d)
                        : ((((size_t)(b * NHEAD + h)) * HDIM + d) * S_LEN + s);
                    o[idx] = f2bf(v);
                }
            }
        }
    }
}

// XCD-locality swizzle: XCD (lid&7) owns m-blocks [8*xcd, 8*xcd+8) for ALL n.
__device__ __forceinline__ void gemm_coords(int& m0, int& n0) {
    const int lid = blockIdx.x + 8 * blockIdx.y;   // 0..511
    const int xcd = lid & 7;
    const int s   = lid >> 3;                      // 0..63
    n0 = (s & 7) * TN;
    m0 = ((s >> 3) + 8 * xcd) * TM;
}

__global__ __launch_bounds__(256) void gemm_qkv(
        const u16* __restrict__ xq, const u16* __restrict__ xk, const u16* __restrict__ xv,
        const u16* __restrict__ wq, const u16* __restrict__ wk, const u16* __restrict__ wv,
        const float* __restrict__ bq, const float* __restrict__ bk, const float* __restrict__ bv,
        u16* __restrict__ Qb, u16* __restrict__ Kb, u16* __restrict__ Vb) {
    int z = blockIdx.z;
    const u16* A   = (z == 0) ? xq : (z == 1) ? xk : xv;
    const u16* W   = (z == 0) ? wq : (z == 1) ? wk : wv;
    const float* b = (z == 0) ? bq : (z == 1) ? bk : bv;
    u16* out       = (z == 0) ? Qb : (z == 1) ? Kb : Vb;
    int m0, n0;
    gemm_coords(m0, n0);
    gemm_body(A, W, b, out, (z == 2) ? 1 : 0, m0, n0);
}

__global__ __launch_bounds__(256) void gemm_one(
        const u16* __restrict__ A, const u16* __restrict__ W,
        const float* __restrict__ bias, void* __restrict__ out, int mode) {
    int m0, n0;
    gemm_coords(m0, n0);
    gemm_body(A, W, bias, out, mode, m0, n0);
}

// ---------- flash attention v6: 2 q-sets per wave, SHARED P buffer ----------
// v5 structure but one P buffer per wave reused sequentially by set A then set
// B (wave-private, DS pipe in-order per wave). LDS = 16+16+8 = 40KB -> 4
// blocks/CU, __launch_bounds__(256,4) -> occupancy back to v4's 16 waves/CU
// while keeping the halved K/V fragment traffic.
__device__ __forceinline__ void exp_write(const f32x4* st, float kq, float sl16,
        bool diag, bool fwd, int md, u16* __restrict__ Pw,
        const int (*poff)[4], const float* br) {
    const float cL = 0.18033688011112042f;   // log2(e)/8
    float kqt[4];
#pragma unroll
    for (int t = 0; t < 4; t++) kqt[t] = kq + (float)t * sl16;
#pragma unroll
    for (int r = 0; r < 4; r++) {
#pragma unroll
        for (int t = 0; t < 4; t++) {
            float p = __builtin_amdgcn_exp2f(fmaf(st[t][r], cL, kqt[t] + br[r]));
            if (diag) {
                bool ok = fwd ? (16 * t - r <= md) : (16 * t - r >= md);
                p = ok ? p : 0.0f;
            }
            Pw[poff[r][t]] = f2bf(p);
        }
    }
}

__device__ __forceinline__ void flash_epilogue(const f32x4* o, const f32x4& osum,
        int q0, int b, int h, int quad, int l16, u16* __restrict__ AO) {
#pragma unroll
    for (int r = 0; r < 4; r++) {
        float inv = 1.0f / osum[r];
        int qg = q0 + quad * 4 + r;
        u16* op = AO + ((size_t)b * S_LEN + qg) * DMODEL + h * HDIM;
#pragma unroll
        for (int dt = 0; dt < 4; dt++)
            op[dt * 16 + l16] = f2bf(o[dt][r] * inv);
    }
}

__global__ __launch_bounds__(256, 4) void flash_kernel(
        const u16* __restrict__ Q, const u16* __restrict__ K,
        const u16* __restrict__ Vt, u16* __restrict__ AO) {
    __shared__ __align__(16) u16 Ksm[2][64 * 64];
    __shared__ __align__(16) u16 Vsm[2][64 * 64];
    __shared__ __align__(16) u16 Psm[4][16 * 64];   // one per wave, shared A/B

    const int tid  = threadIdx.x;
    const int wv   = tid >> 6;
    const int lane = tid & 63;
    const int l16  = lane & 15;
    const int quad = lane >> 4;

    // XCD-pinning: 8 blocks per bh, all on XCD (lid&7)
    const int lid   = blockIdx.x + 8 * blockIdx.y;   // 0..511
    const int xcd   = lid & 7;
    const int slot  = lid >> 3;                       // 0..63
    const int bh    = xcd + 8 * (slot >> 3);          // 0..63
    const int j_idx = slot & 7;                       // 0..7

    const int h    = bh & (NHEAD - 1);
    const int b    = bh >> 4;
    const bool fwd = (h < 8);
    const float sgnf = fwd ? 1.0f : -1.0f;
    const float sl = __builtin_amdgcn_exp2f(-(float)((h & 7) + 1) * 0.5731203125901445f)
                     * 1.4426950408889634f * sgnf;
    const float sl16 = sl * 16.0f;

    const u16* Kg0 = K + (size_t)bh * S_LEN * HDIM;
    const u16* Vg0 = Vt + (size_t)bh * HDIM * S_LEN;

    // staging lane constants
    const int sr = lane >> 3;
    const int sc = (lane & 7) ^ sr;
    const int r0 = 16 * wv;

    // fragment-read swizzled col16
    const int cA = quad ^ (l16 & 7);
    const int cB = (quad + 4) ^ (l16 & 7);

    float br[4];
#pragma unroll
    for (int r = 0; r < 4; r++) br[r] = sl * (float)(l16 - quad * 4 - r);

    // P scatter offsets (u16 units)
    int poff[4][4];
#pragma unroll
    for (int r = 0; r < 4; r++) {
        const int prow = quad * 4 + r;
        const int pr7  = prow & 7;
#pragma unroll
        for (int t = 0; t < 4; t++)
            poff[r][t] = prow * 64 + (((2 * t + (l16 >> 3)) ^ pr7) * 8) + (l16 & 7);
    }

    bf16x8 ones;
#pragma unroll
    for (int j = 0; j < 8; j++) ones[j] = (__bf16)1.0f;

    u16* Pw = &Psm[wv][0];

#pragma unroll 1
    for (int half = 0; half < 2; half++) {
        const int J  = half ? (15 - j_idx) : j_idx;   // 128-query group
        const int q0a = J * 128 + wv * 16;
        const int q0b = q0a + 64;
        const u16* Qp = Q + ((size_t)bh * S_LEN + q0a) * HDIM;
        const bf16x8 aq0a = *(const bf16x8*)(Qp + l16 * HDIM + quad * 8);
        const bf16x8 aq1a = *(const bf16x8*)(Qp + l16 * HDIM + 32 + quad * 8);
        const bf16x8 aq0b = *(const bf16x8*)(Qp + (64 + l16) * HDIM + quad * 8);
        const bf16x8 aq1b = *(const bf16x8*)(Qp + (64 + l16) * HDIM + 32 + quad * 8);

        f32x4 oA[4], oB[4], osA = {}, osB = {};
#pragma unroll
        for (int dt = 0; dt < 4; dt++) { oA[dt] = {}; oB[dt] = {}; }

        const int dga = 2 * J, dgb = 2 * J + 1;
        const int kt0 = fwd ? 0 : dga;
        const int kt1 = fwd ? dgb : (S_LEN / 64 - 1);

        __syncthreads();   // previous half's readers done before overwrite
        const u16* kg = Kg0 + ((size_t)(kt0 * 64) + r0 + sr) * 64 + sc * 8;
        const u16* vg = Vg0 + (size_t)(r0 + sr) * S_LEN + kt0 * 64 + sc * 8;
        gld_lds16(kg,             &Ksm[0][r0 * 64]);
        gld_lds16(kg + 8 * 64,    &Ksm[0][(r0 + 8) * 64]);
        gld_lds16(vg,             &Vsm[0][r0 * 64]);
        gld_lds16(vg + 8 * S_LEN, &Vsm[0][(r0 + 8) * 64]);
        kg += 64 * 64;
        vg += 64;

        float kqa = sl * (float)(kt0 * 64 - q0a) - 16.0f;
        float kqb = kqa - sl * 64.0f;

        int buf = 0;
        for (int kt = kt0; kt <= kt1; ++kt) {
            __builtin_amdgcn_s_waitcnt(0x0F70);   // vmcnt(0): buf staged
            __syncthreads();
            if (kt < kt1) {
                gld_lds16(kg,             &Ksm[buf ^ 1][r0 * 64]);
                gld_lds16(kg + 8 * 64,    &Ksm[buf ^ 1][(r0 + 8) * 64]);
                gld_lds16(vg,             &Vsm[buf ^ 1][r0 * 64]);
                gld_lds16(vg + 8 * S_LEN, &Vsm[buf ^ 1][(r0 + 8) * 64]);
                kg += 64 * 64;
                vg += 64;
            }
            const u16* Ks = &Ksm[buf][0];
            const u16* Vs = &Vsm[buf][0];

            const bool actA = fwd ? (kt <= dga) : true;
            const bool actB = fwd ? true : (kt >= dgb);

            // QK^T, both q-sets, shared K fragments
            f32x4 stA[4], stB[4];
#pragma unroll
            for (int t = 0; t < 4; t++) {
                const u16* kp = Ks + (16 * t + l16) * 64;
                bf16x8 k0 = *(const bf16x8*)(kp + cA * 8);
                bf16x8 k1 = *(const bf16x8*)(kp + cB * 8);
                if (actA) {
                    f32x4 c = {};
                    c = __builtin_amdgcn_mfma_f32_16x16x32_bf16(aq0a, k0, c, 0, 0, 0);
                    c = __builtin_amdgcn_mfma_f32_16x16x32_bf16(aq1a, k1, c, 0, 0, 0);
                    stA[t] = c;
                }
                if (actB) {
                    f32x4 c = {};
                    c = __builtin_amdgcn_mfma_f32_16x16x32_bf16(aq0b, k0, c, 0, 0, 0);
                    c = __builtin_amdgcn_mfma_f32_16x16x32_bf16(aq1b, k1, c, 0, 0, 0);
                    stB[t] = c;
                }
            }

            // V fragments, shared by both q-sets
            bf16x8 v0[4], v1[4];
#pragma unroll
            for (int dt = 0; dt < 4; dt++) {
                const u16* vp = Vs + (dt * 16 + l16) * 64;
                v0[dt] = *(const bf16x8*)(vp + cA * 8);
                v1[dt] = *(const bf16x8*)(vp + cB * 8);
            }

            // ---- set A: P round-trip + PV ----
            if (actA) {
                exp_write(stA, kqa, sl16, kt == dga, fwd,
                          q0a + quad * 4 - kt * 64 - l16, Pw, poff, br);
                __builtin_amdgcn_s_waitcnt(0xC07F);   // lgkmcnt(0)
                bf16x8 pf0 = *(const bf16x8*)(&Pw[l16 * 64 + cA * 8]);
                bf16x8 pf1 = *(const bf16x8*)(&Pw[l16 * 64 + cB * 8]);
#pragma unroll
                for (int dt = 0; dt < 4; dt++) {
                    oA[dt] = __builtin_amdgcn_mfma_f32_16x16x32_bf16(pf0, v0[dt], oA[dt], 0, 0, 0);
                    oA[dt] = __builtin_amdgcn_mfma_f32_16x16x32_bf16(pf1, v1[dt], oA[dt], 0, 0, 0);
                }
                osA = __builtin_amdgcn_mfma_f32_16x16x32_bf16(pf0, ones, osA, 0, 0, 0);
                osA = __builtin_amdgcn_mfma_f32_16x16x32_bf16(pf1, ones, osA, 0, 0, 0);
                __builtin_amdgcn_s_waitcnt(0xC07F);   // reads drained before B overwrites
            }

            // ---- set B: reuse the same P buffer ----
            if (actB) {
                exp_write(stB, kqb, sl16, kt == dgb, fwd,
                          q0b + quad * 4 - kt * 64 - l16, Pw, poff, br);
                __builtin_amdgcn_s_waitcnt(0xC07F);   // lgkmcnt(0)
                bf16x8 pf0 = *(const bf16x8*)(&Pw[l16 * 64 + cA * 8]);
                bf16x8 pf1 = *(const bf16x8*)(&Pw[l16 * 64 + cB * 8]);
#pragma unroll
                for (int dt = 0; dt < 4; dt++) {
                    oB[dt] = __builtin_amdgcn_mfma_f32_16x16x32_bf16(pf0, v0[dt], oB[dt], 0, 0, 0);
                    oB[dt] = __builtin_amdgcn_mfma_f32_16x16x32_bf16(pf1, v1[dt], oB[dt], 0, 0, 0);
                }
                osB = __builtin_amdgcn_mfma_f32_16x16x32_bf16(pf0, ones, osB, 0, 0, 0);
                osB = __builtin_amdgcn_mfma_f32_16x16x32_bf16(pf1, ones, osB, 0, 0, 0);
                __builtin_amdgcn_s_waitcnt(0xC07F);   // reads drained before next iter
            }

            kqa += sl * 64.0f;
            kqb += sl * 64.0f;
            buf ^= 1;
        }

        flash_epilogue(oA, osA, q0a, b, h, quad, l16, AO);
        flash_epilogue(oB, osB, q0b, b, h, quad, l16, AO);
    }
}

extern "C" void kernel_launch(void* const* d_in, const int* in_sizes, int n_in,
                              void* d_out, int out_size, void* d_ws, size_t ws_size,
                              hipStream_t stream) {
    const float* query = (const float*)d_in[0];
    const float* key   = (const float*)d_in[1];
    const float* value = (const float*)d_in[2];
    const float* Wq    = (const float*)d_in[3];
    const float* bq    = (const float*)d_in[4];
    const float* Wk    = (const float*)d_in[5];
    const float* bk    = (const float*)d_in[6];
    const float* Wv    = (const float*)d_in[7];
    const float* bv    = (const float*)d_in[8];
    const float* Wo    = (const float*)d_in[9];
    const float* bo    = (const float*)d_in[10];

    const size_t Xe = (size_t)MTOK * DMODEL;    // 2^23 elems
    const size_t We = (size_t)DMODEL * DMODEL;  // 2^20 elems
    u16* xq  = (u16*)d_ws;
    u16* xk  = xq + Xe;
    u16* xv  = xk + Xe;
    u16* wqb = xv + Xe;
    u16* wkb = wqb + We;
    u16* wvb = wkb + We;
    u16* wob = wvb + We;
    u16* Qb  = wob + We;
    u16* Kb  = Qb + Xe;
    u16* Vb  = Kb + Xe;   // transposed [B,H,D,S]
    u16* AO  = Vb + Xe;

    cast_all<<<dim3(28672), dim3(256), 0, stream>>>(
        query, key, value, Wq, Wk, Wv, Wo,
        xq, xk, xv, wqb, wkb, wvb, wob);

    gemm_qkv<<<dim3(DMODEL / TN, MTOK / TM, 3), dim3(256), 0, stream>>>(
        xq, xk, xv, wqb, wkb, wvb, bq, bk, bv, Qb, Kb, Vb);

    flash_kernel<<<dim3(8, NBATCH * NHEAD), dim3(256), 0, stream>>>(Qb, Kb, Vb, AO);

    gemm_one<<<dim3(DMODEL / TN, MTOK / TM, 1), dim3(256), 0, stream>>>(AO, wob, bo, d_out, 2);
}

// Round 7
// 327.989 us; speedup vs baseline: 2.1646x; 2.1646x over previous
//
#include <hip/hip_runtime.h>
#include <hip/hip_bf16.h>
#include <stdint.h>

typedef unsigned short u16;
typedef __attribute__((ext_vector_type(8))) __bf16 bf16x8;
typedef __attribute__((ext_vector_type(4))) float f32x4;
typedef __attribute__((ext_vector_type(4))) unsigned int u32x4;

#define S_LEN 2048
#define NHEAD 16
#define HDIM 64
#define DMODEL 1024
#define NBATCH 4
#define MTOK (NBATCH * S_LEN)   // 8192

// ---------- helpers ----------
__device__ __forceinline__ u16 f2bf(float f) {
    uint32_t u = __float_as_uint(f);
    u += 0x7fffu + ((u >> 16) & 1u);   // RNE
    return (u16)(u >> 16);
}

// async global->LDS, 16B per lane; lds dest must be wave-uniform base (+lane*16)
__device__ __forceinline__ void gld_lds16(const u16* g, u16* l) {
    __builtin_amdgcn_global_load_lds(
        (const __attribute__((address_space(1))) void*)g,
        (__attribute__((address_space(3))) void*)l, 16, 0, 0);
}

// ---------- fused fp32 -> bf16 cast: all 7 tensors in one launch ----------
__global__ __launch_bounds__(256) void cast_all(
        const float* __restrict__ q, const float* __restrict__ k, const float* __restrict__ v,
        const float* __restrict__ wq, const float* __restrict__ wk,
        const float* __restrict__ wv, const float* __restrict__ wo,
        u16* __restrict__ xq, u16* __restrict__ xk, u16* __restrict__ xv,
        u16* __restrict__ wqb, u16* __restrict__ wkb, u16* __restrict__ wvb,
        u16* __restrict__ wob) {
    size_t idx4 = (size_t)blockIdx.x * 256 + threadIdx.x;   // float4 index
    const float* src;
    u16* dst;
    size_t off;
    if (idx4 < (size_t)3 << 21) {
        int t = (int)(idx4 >> 21);
        off = (idx4 & ((1u << 21) - 1)) * 4;
        src = (t == 0) ? q : (t == 1) ? k : v;
        dst = (t == 0) ? xq : (t == 1) ? xk : xv;
    } else {
        size_t w = idx4 - ((size_t)3 << 21);
        int t = (int)(w >> 18);
        off = (w & ((1u << 18) - 1)) * 4;
        src = (t == 0) ? wq : (t == 1) ? wk : (t == 2) ? wv : wo;
        dst = (t == 0) ? wqb : (t == 1) ? wkb : (t == 2) ? wvb : wob;
    }
    float4 val = *(const float4*)(src + off);
    ushort4 o;
    o.x = f2bf(val.x); o.y = f2bf(val.y); o.z = f2bf(val.z); o.w = f2bf(val.w);
    *(ushort4*)(dst + off) = o;
}

// ---------- GEMM: out[m,n] = sum_k A[m,k]*W[n,k] + bias[n] ----------
// XOR-swizzled LDS: logical col8 c stored at c ^ ((row>>1)&3) -> conflict-free
// b128 fragment reads (R4's fixed-col8 layout was 4x serialized, 6.3M confl).
#define TM 128
#define TN 128

__device__ __forceinline__ void gemm_body(const u16* __restrict__ A,
                                          const u16* __restrict__ W,
                                          const float* __restrict__ bias,
                                          void* __restrict__ outp, int mode,
                                          int m0, int n0) {
    __shared__ __align__(16) u16 As[TM * 32];
    __shared__ __align__(16) u16 Bs[TN * 32];
    const int tid  = threadIdx.x;
    const int lane = tid & 63;
    const int wv   = tid >> 6;
    const int l16  = lane & 15;
    const int quad = lane >> 4;
    const int wm   = (wv >> 1) * 64;
    const int wn   = (wv & 1) * 64;

    f32x4 acc[4][4];
#pragma unroll
    for (int i = 0; i < 4; i++)
#pragma unroll
        for (int j = 0; j < 4; j++) acc[i][j] = {};

    const int arow = wv * 16 + (lane >> 2);
    const int acol = ((lane & 3) ^ ((lane >> 3) & 3)) * 8;   // swizzled source col
    const u16* gA = A + (size_t)(m0 + arow) * DMODEL + acol;
    const u16* gB = W + (size_t)(n0 + arow) * DMODEL + acol;
    u16* lA = As + wv * 16 * 32;   // wave-uniform
    u16* lB = Bs + wv * 16 * 32;

    const int swz = (l16 >> 1) & 3;   // fragment-read swizzle

    for (int kb = 0; kb < DMODEL; kb += 32) {
        gld_lds16(gA + kb, lA);
        gld_lds16(gA + kb + (size_t)64 * DMODEL, lA + 64 * 32);
        gld_lds16(gB + kb, lB);
        gld_lds16(gB + kb + (size_t)64 * DMODEL, lB + 64 * 32);
        __builtin_amdgcn_s_waitcnt(0x0F70);   // vmcnt(0)
        __syncthreads();

        bf16x8 af[4], bfv[4];
#pragma unroll
        for (int i = 0; i < 4; i++)
            af[i] = *(const bf16x8*)(&As[(wm + i * 16 + l16) * 32 + (quad ^ swz) * 8]);
#pragma unroll
        for (int j = 0; j < 4; j++)
            bfv[j] = *(const bf16x8*)(&Bs[(wn + j * 16 + l16) * 32 + (quad ^ swz) * 8]);
#pragma unroll
        for (int i = 0; i < 4; i++)
#pragma unroll
            for (int j = 0; j < 4; j++)
                acc[i][j] = __builtin_amdgcn_mfma_f32_16x16x32_bf16(af[i], bfv[j], acc[i][j], 0, 0, 0);
        __syncthreads();
    }

#pragma unroll
    for (int j = 0; j < 4; j++) {
        int n = n0 + wn + j * 16 + l16;
        float bv = bias[n];
#pragma unroll
        for (int i = 0; i < 4; i++) {
            int mbase = m0 + wm + i * 16 + quad * 4;
#pragma unroll
            for (int r = 0; r < 4; r++) {
                int m = mbase + r;
                float v = acc[i][j][r] + bv;
                if (mode == 2) {
                    ((float*)outp)[(size_t)m * DMODEL + n] = v;
                } else {
                    int b = m >> 11, s = m & (S_LEN - 1);
                    int h = n >> 6, d = n & 63;
                    u16* o = (u16*)outp;
                    size_t idx = (mode == 0)
                        ? ((((size_t)(b * NHEAD + h)) * S_LEN + s) * HDIM + d)
                        : ((((size_t)(b * NHEAD + h)) * HDIM + d) * S_LEN + s);
                    o[idx] = f2bf(v);
                }
            }
        }
    }
}

// XCD-locality swizzle: XCD (lid&7) owns m-blocks [8*xcd, 8*xcd+8) for ALL n.
__device__ __forceinline__ void gemm_coords(int& m0, int& n0) {
    const int lid = blockIdx.x + 8 * blockIdx.y;   // 0..511
    const int xcd = lid & 7;
    const int s   = lid >> 3;                      // 0..63
    n0 = (s & 7) * TN;
    m0 = ((s >> 3) + 8 * xcd) * TM;
}

__global__ __launch_bounds__(256) void gemm_qkv(
        const u16* __restrict__ xq, const u16* __restrict__ xk, const u16* __restrict__ xv,
        const u16* __restrict__ wq, const u16* __restrict__ wk, const u16* __restrict__ wv,
        const float* __restrict__ bq, const float* __restrict__ bk, const float* __restrict__ bv,
        u16* __restrict__ Qb, u16* __restrict__ Kb, u16* __restrict__ Vb) {
    int z = blockIdx.z;
    const u16* A   = (z == 0) ? xq : (z == 1) ? xk : xv;
    const u16* W   = (z == 0) ? wq : (z == 1) ? wk : wv;
    const float* b = (z == 0) ? bq : (z == 1) ? bk : bv;
    u16* out       = (z == 0) ? Qb : (z == 1) ? Kb : Vb;
    int m0, n0;
    gemm_coords(m0, n0);
    gemm_body(A, W, b, out, (z == 2) ? 1 : 0, m0, n0);
}

__global__ __launch_bounds__(256) void gemm_one(
        const u16* __restrict__ A, const u16* __restrict__ W,
        const float* __restrict__ bias, void* __restrict__ out, int mode) {
    int m0, n0;
    gemm_coords(m0, n0);
    gemm_body(A, W, bias, out, mode, m0, n0);
}

// ---------- flash attention (v4, known-good: VGPR 64, zero spill) ----------
// 1 q-tile (16 queries) per wave; 64-key tiles; block-cooperative K/V LDS
// staging double-buffered via global_load_lds; XOR-swizzled layout; fixed-max
// log2-domain softmax; row sums via ones-operand MFMA; {g, 31-g} pairing ->
// exactly 33 iters/block. NOTE (R5/R6): 2-q-sets-per-wave variants need ~120
// live VGPRs and spill catastrophically under occupancy bounds — do not.
__global__ __launch_bounds__(256, 4) void flash_kernel(
        const u16* __restrict__ Q, const u16* __restrict__ K,
        const u16* __restrict__ Vt, u16* __restrict__ AO) {
    __shared__ __align__(16) u16 Ksm[2][64 * 64];
    __shared__ __align__(16) u16 Vsm[2][64 * 64];
    __shared__ __align__(16) u16 Psm[4][16 * 64];

    const int tid  = threadIdx.x;
    const int wv   = tid >> 6;
    const int lane = tid & 63;
    const int l16  = lane & 15;
    const int quad = lane >> 4;

    // XCD-pinning: all 16 blocks of a bh share (linear id % 8)
    const int lid   = blockIdx.x + 16 * blockIdx.y;   // 0..1023
    const int xcd   = lid & 7;
    const int slot  = lid >> 3;                        // 0..127
    const int bh    = xcd + 8 * (slot >> 4);           // 0..63
    const int g_idx = slot & 15;                       // 0..15

    const int h    = bh & (NHEAD - 1);
    const int b    = bh >> 4;
    const bool fwd = (h < 8);
    const int sgn  = fwd ? 1 : -1;
    const float slope2 = __builtin_amdgcn_exp2f(-(float)((h & 7) + 1) * 0.5731203125901445f)
                         * 1.4426950408889634f;
    const float cL = 0.18033688011112042f;   // log2(e)/8

    const u16* Kg = K + (size_t)bh * S_LEN * HDIM;
    const u16* Vg = Vt + (size_t)bh * HDIM * S_LEN;

    // staging lane constants: 8 lanes per row, col16 = (lane&7) ^ (lane>>3)
    const int sr = lane >> 3;
    const int sc = (lane & 7) ^ sr;
    const int r0 = 16 * wv;          // this wave stages rows r0..r0+15

    // fragment-read swizzled col16
    const int cA = quad ^ (l16 & 7);          // global col16 = quad
    const int cB = (quad + 4) ^ (l16 & 7);    // global col16 = quad+4

    // ALiBi per-(t,r) in-tile offset, fixed max 16 folded
    float brt[4][4];
#pragma unroll
    for (int t = 0; t < 4; t++)
#pragma unroll
        for (int r = 0; r < 4; r++)
            brt[t][r] = slope2 * (float)(sgn * (16 * t + l16 - (quad * 4 + r))) - 16.0f;

    // P scatter offsets (u16 units) — constant across all iterations
    int poff[4][4];
#pragma unroll
    for (int r = 0; r < 4; r++) {
        const int prow = quad * 4 + r;
        const int pr7  = prow & 7;
#pragma unroll
        for (int t = 0; t < 4; t++)
            poff[r][t] = prow * 64 + (((2 * t + (l16 >> 3)) ^ pr7) * 8) + (l16 & 7);
    }

    bf16x8 ones;
#pragma unroll
    for (int j = 0; j < 8; j++) ones[j] = (__bf16)1.0f;

    const float dkq = slope2 * (float)(sgn * 64);

#pragma unroll 1
    for (int half = 0; half < 2; half++) {
        const int g  = half ? (31 - g_idx) : g_idx;    // 64-query group 0..31
        const int q0 = g * 64 + wv * 16;
        const u16* Qp = Q + ((size_t)bh * S_LEN + q0) * HDIM;
        const bf16x8 aq0 = *(const bf16x8*)(Qp + l16 * HDIM + quad * 8);
        const bf16x8 aq1 = *(const bf16x8*)(Qp + l16 * HDIM + 32 + quad * 8);

        f32x4 o[4], osum = {};
#pragma unroll
        for (int dt = 0; dt < 4; dt++) o[dt] = {};

        const int kt0 = fwd ? 0 : g;
        const int kt1 = fwd ? g : (S_LEN / 64 - 1);

        __syncthreads();   // previous half's readers done before overwrite
        // incremental staging pointers
        const u16* kg = Kg + ((size_t)(kt0 * 64) + r0 + sr) * 64 + sc * 8;
        const u16* vg = Vg + (size_t)(r0 + sr) * S_LEN + kt0 * 64 + sc * 8;
        gld_lds16(kg,              &Ksm[0][r0 * 64]);
        gld_lds16(kg + 8 * 64,     &Ksm[0][(r0 + 8) * 64]);
        gld_lds16(vg,              &Vsm[0][r0 * 64]);
        gld_lds16(vg + 8 * S_LEN,  &Vsm[0][(r0 + 8) * 64]);
        kg += 64 * 64;
        vg += 64;

        float kq = slope2 * (float)(sgn * (kt0 * 64 - q0));

        int buf = 0;
        for (int kt = kt0; kt <= kt1; ++kt) {
            __builtin_amdgcn_s_waitcnt(0x0F70);   // vmcnt(0): buf staged
            __syncthreads();
            if (kt < kt1) {   // stage next tile into the other buffer
                gld_lds16(kg,             &Ksm[buf ^ 1][r0 * 64]);
                gld_lds16(kg + 8 * 64,    &Ksm[buf ^ 1][(r0 + 8) * 64]);
                gld_lds16(vg,             &Vsm[buf ^ 1][r0 * 64]);
                gld_lds16(vg + 8 * S_LEN, &Vsm[buf ^ 1][(r0 + 8) * 64]);
                kg += 64 * 64;
                vg += 64;
            }
            const u16* Ks = &Ksm[buf][0];
            const u16* Vs = &Vsm[buf][0];

            // QK^T from LDS
            f32x4 st[4];
#pragma unroll
            for (int t = 0; t < 4; t++) {
                const u16* kp = Ks + (16 * t + l16) * 64;
                bf16x8 k0 = *(const bf16x8*)(kp + cA * 8);
                bf16x8 k1 = *(const bf16x8*)(kp + cB * 8);
                f32x4 c = {};
                c = __builtin_amdgcn_mfma_f32_16x16x32_bf16(aq0, k0, c, 0, 0, 0);
                c = __builtin_amdgcn_mfma_f32_16x16x32_bf16(aq1, k1, c, 0, 0, 0);
                st[t] = c;
            }

            float p[4][4];
            if (kt == g) {   // diagonal tile: explicit mask
#pragma unroll
                for (int r = 0; r < 4; r++) {
                    const int qg = q0 + quad * 4 + r;
#pragma unroll
                    for (int t = 0; t < 4; t++) {
                        const int kg2 = kt * 64 + 16 * t + l16;
                        const bool ok = fwd ? (kg2 <= qg) : (kg2 >= qg);
                        float s2 = fmaf(st[t][r], cL, brt[t][r] + kq);
                        p[t][r] = ok ? __builtin_amdgcn_exp2f(s2) : 0.0f;
                    }
                }
            } else {
#pragma unroll
                for (int r = 0; r < 4; r++)
#pragma unroll
                    for (int t = 0; t < 4; t++)
                        p[t][r] = __builtin_amdgcn_exp2f(fmaf(st[t][r], cL, brt[t][r] + kq));
            }
            kq += dkq;

            // P (C-layout) -> swizzled LDS -> A-operand layout (wave-private)
            u16* Pw = &Psm[wv][0];
#pragma unroll
            for (int r = 0; r < 4; r++)
#pragma unroll
                for (int t = 0; t < 4; t++)
                    Pw[poff[r][t]] = f2bf(p[t][r]);
            __builtin_amdgcn_s_waitcnt(0xC07F);   // lgkmcnt(0); wave-private
            bf16x8 pf0 = *(const bf16x8*)(&Pw[l16 * 64 + cA * 8]);
            bf16x8 pf1 = *(const bf16x8*)(&Pw[l16 * 64 + cB * 8]);

            // PV from LDS V
#pragma unroll
            for (int dt = 0; dt < 4; dt++) {
                const u16* vp = Vs + (dt * 16 + l16) * 64;
                bf16x8 v0 = *(const bf16x8*)(vp + cA * 8);
                bf16x8 v1 = *(const bf16x8*)(vp + cB * 8);
                o[dt] = __builtin_amdgcn_mfma_f32_16x16x32_bf16(pf0, v0, o[dt], 0, 0, 0);
                o[dt] = __builtin_amdgcn_mfma_f32_16x16x32_bf16(pf1, v1, o[dt], 0, 0, 0);
            }
            osum = __builtin_amdgcn_mfma_f32_16x16x32_bf16(pf0, ones, osum, 0, 0, 0);
            osum = __builtin_amdgcn_mfma_f32_16x16x32_bf16(pf1, ones, osum, 0, 0, 0);
            buf ^= 1;
        }

        // epilogue: AO[b, s, h*64+d] bf16
#pragma unroll
        for (int r = 0; r < 4; r++) {
            float inv = 1.0f / osum[r];
            int qg = q0 + quad * 4 + r;
            u16* op = AO + ((size_t)b * S_LEN + qg) * DMODEL + h * HDIM;
#pragma unroll
            for (int dt = 0; dt < 4; dt++)
                op[dt * 16 + l16] = f2bf(o[dt][r] * inv);
        }
    }
}

extern "C" void kernel_launch(void* const* d_in, const int* in_sizes, int n_in,
                              void* d_out, int out_size, void* d_ws, size_t ws_size,
                              hipStream_t stream) {
    const float* query = (const float*)d_in[0];
    const float* key   = (const float*)d_in[1];
    const float* value = (const float*)d_in[2];
    const float* Wq    = (const float*)d_in[3];
    const float* bq    = (const float*)d_in[4];
    const float* Wk    = (const float*)d_in[5];
    const float* bk    = (const float*)d_in[6];
    const float* Wv    = (const float*)d_in[7];
    const float* bv    = (const float*)d_in[8];
    const float* Wo    = (const float*)d_in[9];
    const float* bo    = (const float*)d_in[10];

    const size_t Xe = (size_t)MTOK * DMODEL;    // 2^23 elems
    const size_t We = (size_t)DMODEL * DMODEL;  // 2^20 elems
    u16* xq  = (u16*)d_ws;
    u16* xk  = xq + Xe;
    u16* xv  = xk + Xe;
    u16* wqb = xv + Xe;
    u16* wkb = wqb + We;
    u16* wvb = wkb + We;
    u16* wob = wvb + We;
    u16* Qb  = wob + We;
    u16* Kb  = Qb + Xe;
    u16* Vb  = Kb + Xe;   // transposed [B,H,D,S]
    u16* AO  = Vb + Xe;

    cast_all<<<dim3(28672), dim3(256), 0, stream>>>(
        query, key, value, Wq, Wk, Wv, Wo,
        xq, xk, xv, wqb, wkb, wvb, wob);

    gemm_qkv<<<dim3(DMODEL / TN, MTOK / TM, 3), dim3(256), 0, stream>>>(
        xq, xk, xv, wqb, wkb, wvb, bq, bk, bv, Qb, Kb, Vb);

    flash_kernel<<<dim3(16, NBATCH * NHEAD), dim3(256), 0, stream>>>(Qb, Kb, Vb, AO);

    gemm_one<<<dim3(DMODEL / TN, MTOK / TM, 1), dim3(256), 0, stream>>>(AO, wob, bo, d_out, 2);
}

// Round 8
// 327.597 us; speedup vs baseline: 2.1672x; 1.0012x over previous
//
#include <hip/hip_runtime.h>
#include <hip/hip_bf16.h>
#include <stdint.h>

typedef unsigned short u16;
typedef __attribute__((ext_vector_type(8))) __bf16 bf16x8;
typedef __attribute__((ext_vector_type(4))) float f32x4;
typedef __attribute__((ext_vector_type(4))) unsigned int u32x4;

#define S_LEN 2048
#define NHEAD 16
#define HDIM 64
#define DMODEL 1024
#define NBATCH 4
#define MTOK (NBATCH * S_LEN)   // 8192

// ---------- helpers ----------
__device__ __forceinline__ u16 f2bf(float f) {
    uint32_t u = __float_as_uint(f);
    u += 0x7fffu + ((u >> 16) & 1u);   // RNE
    return (u16)(u >> 16);
}

// async global->LDS, 16B per lane; lds dest must be wave-uniform base (+lane*16)
__device__ __forceinline__ void gld_lds16(const u16* g, u16* l) {
    __builtin_amdgcn_global_load_lds(
        (const __attribute__((address_space(1))) void*)g,
        (__attribute__((address_space(3))) void*)l, 16, 0, 0);
}

// ---------- fused fp32 -> bf16 cast: all 7 tensors in one launch ----------
__global__ __launch_bounds__(256) void cast_all(
        const float* __restrict__ q, const float* __restrict__ k, const float* __restrict__ v,
        const float* __restrict__ wq, const float* __restrict__ wk,
        const float* __restrict__ wv, const float* __restrict__ wo,
        u16* __restrict__ xq, u16* __restrict__ xk, u16* __restrict__ xv,
        u16* __restrict__ wqb, u16* __restrict__ wkb, u16* __restrict__ wvb,
        u16* __restrict__ wob) {
    size_t idx4 = (size_t)blockIdx.x * 256 + threadIdx.x;   // float4 index
    const float* src;
    u16* dst;
    size_t off;
    if (idx4 < (size_t)3 << 21) {
        int t = (int)(idx4 >> 21);
        off = (idx4 & ((1u << 21) - 1)) * 4;
        src = (t == 0) ? q : (t == 1) ? k : v;
        dst = (t == 0) ? xq : (t == 1) ? xk : xv;
    } else {
        size_t w = idx4 - ((size_t)3 << 21);
        int t = (int)(w >> 18);
        off = (w & ((1u << 18) - 1)) * 4;
        src = (t == 0) ? wq : (t == 1) ? wk : (t == 2) ? wv : wo;
        dst = (t == 0) ? wqb : (t == 1) ? wkb : (t == 2) ? wvb : wob;
    }
    float4 val = *(const float4*)(src + off);
    ushort4 o;
    o.x = f2bf(val.x); o.y = f2bf(val.y); o.z = f2bf(val.z); o.w = f2bf(val.w);
    *(ushort4*)(dst + off) = o;
}

// ---------- GEMM: out[m,n] = sum_k A[m,k]*W[n,k] + bias[n] ----------
// BK=64: 32 MFMA per barrier (was 16) to amortize the vmcnt(0)+barrier drain
// (R7 profile: MfmaUtil 24%, the 2-barrier drain dominated at BK=32).
// LDS layout = flash kernel's proven 64-col XOR swizzle: logical col8 c of row
// r stored at slot c ^ (r&7); staged by fetching global col (lane&7)^(lane>>3);
// fragment b128 reads at quad^(l16&7) / (quad+4)^(l16&7) — 0 conflicts (R7).
#define TM 128
#define TN 128
#define BK 64

__device__ __forceinline__ void gemm_body(const u16* __restrict__ A,
                                          const u16* __restrict__ W,
                                          const float* __restrict__ bias,
                                          void* __restrict__ outp, int mode,
                                          int m0, int n0) {
    __shared__ __align__(16) u16 As[TM * BK];
    __shared__ __align__(16) u16 Bs[TN * BK];
    const int tid  = threadIdx.x;
    const int lane = tid & 63;
    const int wv   = tid >> 6;
    const int l16  = lane & 15;
    const int quad = lane >> 4;
    const int wm   = (wv >> 1) * 64;
    const int wn   = (wv & 1) * 64;

    f32x4 acc[4][4];
#pragma unroll
    for (int i = 0; i < 4; i++)
#pragma unroll
        for (int j = 0; j < 4; j++) acc[i][j] = {};

    // staging: one gld covers 8 rows x 64 cols (64 lanes x 16B). 8 lanes/row.
    const int sr  = lane >> 3;                 // row within 8-row group
    const int sc7 = (lane & 7) ^ sr;           // swizzled source col8
    // wave wv stages rows [wv*32, wv*32+32) of A and B (4 glds each)
    const u16* gA = A + (size_t)(m0 + wv * 32 + sr) * DMODEL + sc7 * 8;
    const u16* gB = W + (size_t)(n0 + wv * 32 + sr) * DMODEL + sc7 * 8;
    u16* lA = As + wv * 32 * BK;   // wave-uniform
    u16* lB = Bs + wv * 32 * BK;

    // fragment-read swizzled col8
    const int cA = quad ^ (l16 & 7);          // k in [0,32)
    const int cB = (quad + 4) ^ (l16 & 7);    // k in [32,64)

    for (int kb = 0; kb < DMODEL; kb += BK) {
#pragma unroll
        for (int g = 0; g < 4; g++)
            gld_lds16(gA + kb + (size_t)(g * 8) * DMODEL, lA + g * 8 * BK);
#pragma unroll
        for (int g = 0; g < 4; g++)
            gld_lds16(gB + kb + (size_t)(g * 8) * DMODEL, lB + g * 8 * BK);
        __builtin_amdgcn_s_waitcnt(0x0F70);   // vmcnt(0)
        __syncthreads();

        bf16x8 af0[4], af1[4], bf0[4], bf1[4];
#pragma unroll
        for (int i = 0; i < 4; i++) {
            const u16* ap = &As[(wm + i * 16 + l16) * BK];
            af0[i] = *(const bf16x8*)(ap + cA * 8);
            af1[i] = *(const bf16x8*)(ap + cB * 8);
        }
#pragma unroll
        for (int j = 0; j < 4; j++) {
            const u16* bp = &Bs[(wn + j * 16 + l16) * BK];
            bf0[j] = *(const bf16x8*)(bp + cA * 8);
            bf1[j] = *(const bf16x8*)(bp + cB * 8);
        }
#pragma unroll
        for (int i = 0; i < 4; i++)
#pragma unroll
            for (int j = 0; j < 4; j++)
                acc[i][j] = __builtin_amdgcn_mfma_f32_16x16x32_bf16(af0[i], bf0[j], acc[i][j], 0, 0, 0);
#pragma unroll
        for (int i = 0; i < 4; i++)
#pragma unroll
            for (int j = 0; j < 4; j++)
                acc[i][j] = __builtin_amdgcn_mfma_f32_16x16x32_bf16(af1[i], bf1[j], acc[i][j], 0, 0, 0);
        __syncthreads();
    }

#pragma unroll
    for (int j = 0; j < 4; j++) {
        int n = n0 + wn + j * 16 + l16;
        float bv = bias[n];
#pragma unroll
        for (int i = 0; i < 4; i++) {
            int mbase = m0 + wm + i * 16 + quad * 4;
#pragma unroll
            for (int r = 0; r < 4; r++) {
                int m = mbase + r;
                float v = acc[i][j][r] + bv;
                if (mode == 2) {
                    ((float*)outp)[(size_t)m * DMODEL + n] = v;
                } else {
                    int b = m >> 11, s = m & (S_LEN - 1);
                    int h = n >> 6, d = n & 63;
                    u16* o = (u16*)outp;
                    size_t idx = (mode == 0)
                        ? ((((size_t)(b * NHEAD + h)) * S_LEN + s) * HDIM + d)
                        : ((((size_t)(b * NHEAD + h)) * HDIM + d) * S_LEN + s);
                    o[idx] = f2bf(v);
                }
            }
        }
    }
}

// XCD-locality swizzle: XCD (lid&7) owns m-blocks [8*xcd, 8*xcd+8) for ALL n.
__device__ __forceinline__ void gemm_coords(int& m0, int& n0) {
    const int lid = blockIdx.x + 8 * blockIdx.y;   // 0..511
    const int xcd = lid & 7;
    const int s   = lid >> 3;                      // 0..63
    n0 = (s & 7) * TN;
    m0 = ((s >> 3) + 8 * xcd) * TM;
}

__global__ __launch_bounds__(256) void gemm_qkv(
        const u16* __restrict__ xq, const u16* __restrict__ xk, const u16* __restrict__ xv,
        const u16* __restrict__ wq, const u16* __restrict__ wk, const u16* __restrict__ wv,
        const float* __restrict__ bq, const float* __restrict__ bk, const float* __restrict__ bv,
        u16* __restrict__ Qb, u16* __restrict__ Kb, u16* __restrict__ Vb) {
    int z = blockIdx.z;
    const u16* A   = (z == 0) ? xq : (z == 1) ? xk : xv;
    const u16* W   = (z == 0) ? wq : (z == 1) ? wk : wv;
    const float* b = (z == 0) ? bq : (z == 1) ? bk : bv;
    u16* out       = (z == 0) ? Qb : (z == 1) ? Kb : Vb;
    int m0, n0;
    gemm_coords(m0, n0);
    gemm_body(A, W, b, out, (z == 2) ? 1 : 0, m0, n0);
}

__global__ __launch_bounds__(256) void gemm_one(
        const u16* __restrict__ A, const u16* __restrict__ W,
        const float* __restrict__ bias, void* __restrict__ out, int mode) {
    int m0, n0;
    gemm_coords(m0, n0);
    gemm_body(A, W, bias, out, mode, m0, n0);
}

// ---------- flash attention (v4, known-good: VGPR 64, zero spill) ----------
// 1 q-tile (16 queries) per wave; 64-key tiles; block-cooperative K/V LDS
// staging double-buffered via global_load_lds; XOR-swizzled layout; fixed-max
// log2-domain softmax; row sums via ones-operand MFMA; {g, 31-g} pairing ->
// exactly 33 iters/block. NOTE (R5/R6): 2-q-sets-per-wave variants need ~120
// live VGPRs and spill catastrophically under occupancy bounds — do not.
__global__ __launch_bounds__(256, 4) void flash_kernel(
        const u16* __restrict__ Q, const u16* __restrict__ K,
        const u16* __restrict__ Vt, u16* __restrict__ AO) {
    __shared__ __align__(16) u16 Ksm[2][64 * 64];
    __shared__ __align__(16) u16 Vsm[2][64 * 64];
    __shared__ __align__(16) u16 Psm[4][16 * 64];

    const int tid  = threadIdx.x;
    const int wv   = tid >> 6;
    const int lane = tid & 63;
    const int l16  = lane & 15;
    const int quad = lane >> 4;

    // XCD-pinning: all 16 blocks of a bh share (linear id % 8)
    const int lid   = blockIdx.x + 16 * blockIdx.y;   // 0..1023
    const int xcd   = lid & 7;
    const int slot  = lid >> 3;                        // 0..127
    const int bh    = xcd + 8 * (slot >> 4);           // 0..63
    const int g_idx = slot & 15;                       // 0..15

    const int h    = bh & (NHEAD - 1);
    const int b    = bh >> 4;
    const bool fwd = (h < 8);
    const int sgn  = fwd ? 1 : -1;
    const float slope2 = __builtin_amdgcn_exp2f(-(float)((h & 7) + 1) * 0.5731203125901445f)
                         * 1.4426950408889634f;
    const float cL = 0.18033688011112042f;   // log2(e)/8

    const u16* Kg = K + (size_t)bh * S_LEN * HDIM;
    const u16* Vg = Vt + (size_t)bh * HDIM * S_LEN;

    // staging lane constants: 8 lanes per row, col16 = (lane&7) ^ (lane>>3)
    const int sr = lane >> 3;
    const int sc = (lane & 7) ^ sr;
    const int r0 = 16 * wv;          // this wave stages rows r0..r0+15

    // fragment-read swizzled col16
    const int cA = quad ^ (l16 & 7);          // global col16 = quad
    const int cB = (quad + 4) ^ (l16 & 7);    // global col16 = quad+4

    // ALiBi per-(t,r) in-tile offset, fixed max 16 folded
    float brt[4][4];
#pragma unroll
    for (int t = 0; t < 4; t++)
#pragma unroll
        for (int r = 0; r < 4; r++)
            brt[t][r] = slope2 * (float)(sgn * (16 * t + l16 - (quad * 4 + r))) - 16.0f;

    // P scatter offsets (u16 units) — constant across all iterations
    int poff[4][4];
#pragma unroll
    for (int r = 0; r < 4; r++) {
        const int prow = quad * 4 + r;
        const int pr7  = prow & 7;
#pragma unroll
        for (int t = 0; t < 4; t++)
            poff[r][t] = prow * 64 + (((2 * t + (l16 >> 3)) ^ pr7) * 8) + (l16 & 7);
    }

    bf16x8 ones;
#pragma unroll
    for (int j = 0; j < 8; j++) ones[j] = (__bf16)1.0f;

    const float dkq = slope2 * (float)(sgn * 64);

#pragma unroll 1
    for (int half = 0; half < 2; half++) {
        const int g  = half ? (31 - g_idx) : g_idx;    // 64-query group 0..31
        const int q0 = g * 64 + wv * 16;
        const u16* Qp = Q + ((size_t)bh * S_LEN + q0) * HDIM;
        const bf16x8 aq0 = *(const bf16x8*)(Qp + l16 * HDIM + quad * 8);
        const bf16x8 aq1 = *(const bf16x8*)(Qp + l16 * HDIM + 32 + quad * 8);

        f32x4 o[4], osum = {};
#pragma unroll
        for (int dt = 0; dt < 4; dt++) o[dt] = {};

        const int kt0 = fwd ? 0 : g;
        const int kt1 = fwd ? g : (S_LEN / 64 - 1);

        __syncthreads();   // previous half's readers done before overwrite
        // incremental staging pointers
        const u16* kg = Kg + ((size_t)(kt0 * 64) + r0 + sr) * 64 + sc * 8;
        const u16* vg = Vg + (size_t)(r0 + sr) * S_LEN + kt0 * 64 + sc * 8;
        gld_lds16(kg,              &Ksm[0][r0 * 64]);
        gld_lds16(kg + 8 * 64,     &Ksm[0][(r0 + 8) * 64]);
        gld_lds16(vg,              &Vsm[0][r0 * 64]);
        gld_lds16(vg + 8 * S_LEN,  &Vsm[0][(r0 + 8) * 64]);
        kg += 64 * 64;
        vg += 64;

        float kq = slope2 * (float)(sgn * (kt0 * 64 - q0));

        int buf = 0;
        for (int kt = kt0; kt <= kt1; ++kt) {
            __builtin_amdgcn_s_waitcnt(0x0F70);   // vmcnt(0): buf staged
            __syncthreads();
            if (kt < kt1) {   // stage next tile into the other buffer
                gld_lds16(kg,             &Ksm[buf ^ 1][r0 * 64]);
                gld_lds16(kg + 8 * 64,    &Ksm[buf ^ 1][(r0 + 8) * 64]);
                gld_lds16(vg,             &Vsm[buf ^ 1][r0 * 64]);
                gld_lds16(vg + 8 * S_LEN, &Vsm[buf ^ 1][(r0 + 8) * 64]);
                kg += 64 * 64;
                vg += 64;
            }
            const u16* Ks = &Ksm[buf][0];
            const u16* Vs = &Vsm[buf][0];

            // QK^T from LDS
            f32x4 st[4];
#pragma unroll
            for (int t = 0; t < 4; t++) {
                const u16* kp = Ks + (16 * t + l16) * 64;
                bf16x8 k0 = *(const bf16x8*)(kp + cA * 8);
                bf16x8 k1 = *(const bf16x8*)(kp + cB * 8);
                f32x4 c = {};
                c = __builtin_amdgcn_mfma_f32_16x16x32_bf16(aq0, k0, c, 0, 0, 0);
                c = __builtin_amdgcn_mfma_f32_16x16x32_bf16(aq1, k1, c, 0, 0, 0);
                st[t] = c;
            }

            float p[4][4];
            if (kt == g) {   // diagonal tile: explicit mask
#pragma unroll
                for (int r = 0; r < 4; r++) {
                    const int qg = q0 + quad * 4 + r;
#pragma unroll
                    for (int t = 0; t < 4; t++) {
                        const int kg2 = kt * 64 + 16 * t + l16;
                        const bool ok = fwd ? (kg2 <= qg) : (kg2 >= qg);
                        float s2 = fmaf(st[t][r], cL, brt[t][r] + kq);
                        p[t][r] = ok ? __builtin_amdgcn_exp2f(s2) : 0.0f;
                    }
                }
            } else {
#pragma unroll
                for (int r = 0; r < 4; r++)
#pragma unroll
                    for (int t = 0; t < 4; t++)
                        p[t][r] = __builtin_amdgcn_exp2f(fmaf(st[t][r], cL, brt[t][r] + kq));
            }
            kq += dkq;

            // P (C-layout) -> swizzled LDS -> A-operand layout (wave-private)
            u16* Pw = &Psm[wv][0];
#pragma unroll
            for (int r = 0; r < 4; r++)
#pragma unroll
                for (int t = 0; t < 4; t++)
                    Pw[poff[r][t]] = f2bf(p[t][r]);
            __builtin_amdgcn_s_waitcnt(0xC07F);   // lgkmcnt(0); wave-private
            bf16x8 pf0 = *(const bf16x8*)(&Pw[l16 * 64 + cA * 8]);
            bf16x8 pf1 = *(const bf16x8*)(&Pw[l16 * 64 + cB * 8]);

            // PV from LDS V
#pragma unroll
            for (int dt = 0; dt < 4; dt++) {
                const u16* vp = Vs + (dt * 16 + l16) * 64;
                bf16x8 v0 = *(const bf16x8*)(vp + cA * 8);
                bf16x8 v1 = *(const bf16x8*)(vp + cB * 8);
                o[dt] = __builtin_amdgcn_mfma_f32_16x16x32_bf16(pf0, v0, o[dt], 0, 0, 0);
                o[dt] = __builtin_amdgcn_mfma_f32_16x16x32_bf16(pf1, v1, o[dt], 0, 0, 0);
            }
            osum = __builtin_amdgcn_mfma_f32_16x16x32_bf16(pf0, ones, osum, 0, 0, 0);
            osum = __builtin_amdgcn_mfma_f32_16x16x32_bf16(pf1, ones, osum, 0, 0, 0);
            buf ^= 1;
        }

        // epilogue: AO[b, s, h*64+d] bf16
#pragma unroll
        for (int r = 0; r < 4; r++) {
            float inv = 1.0f / osum[r];
            int qg = q0 + quad * 4 + r;
            u16* op = AO + ((size_t)b * S_LEN + qg) * DMODEL + h * HDIM;
#pragma unroll
            for (int dt = 0; dt < 4; dt++)
                op[dt * 16 + l16] = f2bf(o[dt][r] * inv);
        }
    }
}

extern "C" void kernel_launch(void* const* d_in, const int* in_sizes, int n_in,
                              void* d_out, int out_size, void* d_ws, size_t ws_size,
                              hipStream_t stream) {
    const float* query = (const float*)d_in[0];
    const float* key   = (const float*)d_in[1];
    const float* value = (const float*)d_in[2];
    const float* Wq    = (const float*)d_in[3];
    const float* bq    = (const float*)d_in[4];
    const float* Wk    = (const float*)d_in[5];
    const float* bk    = (const float*)d_in[6];
    const float* Wv    = (const float*)d_in[7];
    const float* bv    = (const float*)d_in[8];
    const float* Wo    = (const float*)d_in[9];
    const float* bo    = (const float*)d_in[10];

    const size_t Xe = (size_t)MTOK * DMODEL;    // 2^23 elems
    const size_t We = (size_t)DMODEL * DMODEL;  // 2^20 elems
    u16* xq  = (u16*)d_ws;
    u16* xk  = xq + Xe;
    u16* xv  = xk + Xe;
    u16* wqb = xv + Xe;
    u16* wkb = wqb + We;
    u16* wvb = wkb + We;
    u16* wob = wvb + We;
    u16* Qb  = wob + We;
    u16* Kb  = Qb + Xe;
    u16* Vb  = Kb + Xe;   // transposed [B,H,D,S]
    u16* AO  = Vb + Xe;

    cast_all<<<dim3(28672), dim3(256), 0, stream>>>(
        query, key, value, Wq, Wk, Wv, Wo,
        xq, xk, xv, wqb, wkb, wvb, wob);

    gemm_qkv<<<dim3(DMODEL / TN, MTOK / TM, 3), dim3(256), 0, stream>>>(
        xq, xk, xv, wqb, wkb, wvb, bq, bk, bv, Qb, Kb, Vb);

    flash_kernel<<<dim3(16, NBATCH * NHEAD), dim3(256), 0, stream>>>(Qb, Kb, Vb, AO);

    gemm_one<<<dim3(DMODEL / TN, MTOK / TM, 1), dim3(256), 0, stream>>>(AO, wob, bo, d_out, 2);
}